// Round 1
// baseline (1588.288 us; speedup 1.0000x reference)
//
#include <hip/hip_runtime.h>

// IcoPool: out[b,f,v] = mean_{k<7} x[b,f,idx[v,k]]
// x: (8, 64, 163842) f32, idx: (40962, 7) int32 (harness converts int64 -> int32)
// out: (8, 64, 40962) f32

constexpr int B = 8, F = 64, V_IN = 163842, V_OUT = 40962, K = 7;
constexpr int ROWS = B * F;   // 512
constexpr int RPB  = 8;       // rows per block (amortize index loads, L2 row reuse)
constexpr int TPB  = 256;

__global__ __launch_bounds__(TPB) void icopool_gather(
    const float* __restrict__ x,
    const int*   __restrict__ nidx,
    float*       __restrict__ out)
{
    const int v  = blockIdx.x * TPB + threadIdx.x;
    const int r0 = blockIdx.y * RPB;
    if (v >= V_OUT) return;

    const int base = v * K;
    // 7 index loads per thread, reused across RPB rows.
    const int i0 = nidx[base + 0];
    const int i1 = nidx[base + 1];
    const int i2 = nidx[base + 2];
    const int i3 = nidx[base + 3];
    const int i4 = nidx[base + 4];
    const int i5 = nidx[base + 5];
    const int i6 = nidx[base + 6];

    for (int r = 0; r < RPB; ++r) {
        const float* xr = x + (size_t)(r0 + r) * V_IN;
        float s = xr[i0] + xr[i1] + xr[i2] + xr[i3] + xr[i4] + xr[i5] + xr[i6];
        out[(size_t)(r0 + r) * V_OUT + v] = s * (1.0f / 7.0f);
    }
}

extern "C" void kernel_launch(void* const* d_in, const int* in_sizes, int n_in,
                              void* d_out, int out_size, void* d_ws, size_t ws_size,
                              hipStream_t stream) {
    const float* x    = (const float*)d_in[0];
    const int*   nidx = (const int*)d_in[1];
    float*       out  = (float*)d_out;

    dim3 grid((V_OUT + TPB - 1) / TPB, ROWS / RPB);
    icopool_gather<<<grid, dim3(TPB), 0, stream>>>(x, nidx, out);
}

// Round 2
// 954.484 us; speedup vs baseline: 1.6640x; 1.6640x over previous
//
#include <hip/hip_runtime.h>

// IcoPool: out[b,f,v] = mean_{k<7} x[b,f,idx[v,k]]
// x: (8, 64, 163842) f32, idx: (40962, 7) int32, out: (8, 64, 40962) f32
//
// Key idea: partition the 512 rows across the 8 XCDs (xcd = blockIdx & 7 is the
// HW round-robin). Each row of x (655 KB) then lives in exactly one XCD's 4 MB L2
// and is fetched from HBM once. Within an XCD, consecutive blocks sweep all
// v-blocks of one row-group before advancing, keeping the live window small:
// RPB=2 -> ~2.1 MB row window + 1.15 MB idx < 4 MB L2.

constexpr int B = 8, F = 64, V_IN = 163842, V_OUT = 40962, K = 7;
constexpr int ROWS = B * F;          // 512
constexpr int RPB  = 2;              // rows per block
constexpr int TPB  = 256;
constexpr int VB   = (V_OUT + TPB - 1) / TPB;       // 161 v-blocks per row-group
constexpr int RGS  = ROWS / RPB;                    // 256 row-groups
constexpr int RG_PER_XCD = RGS / 8;                 // 32
constexpr int BLOCKS = RGS * VB;                    // 41216

__global__ __launch_bounds__(TPB) void icopool_gather(
    const float* __restrict__ x,
    const int*   __restrict__ nidx,
    float*       __restrict__ out)
{
    const int b        = blockIdx.x;
    const int xcd      = b & 7;          // HW: round-robin XCD assignment
    const int j        = b >> 3;         // per-XCD sequence number
    const int rg_local = j / VB;         // row-group index within this XCD
    const int vb       = j % VB;         // v-block: fastest-varying -> same rows stay hot
    const int rg       = xcd * RG_PER_XCD + rg_local;
    const int r0       = rg * RPB;

    const int v = vb * TPB + threadIdx.x;
    if (v >= V_OUT) return;

    const int base = v * K;
    const int i0 = nidx[base + 0];
    const int i1 = nidx[base + 1];
    const int i2 = nidx[base + 2];
    const int i3 = nidx[base + 3];
    const int i4 = nidx[base + 4];
    const int i5 = nidx[base + 5];
    const int i6 = nidx[base + 6];

    #pragma unroll
    for (int r = 0; r < RPB; ++r) {
        const float* xr = x + (size_t)(r0 + r) * V_IN;
        float s = xr[i0] + xr[i1] + xr[i2] + xr[i3] + xr[i4] + xr[i5] + xr[i6];
        // non-temporal: don't let the streamed output evict the x row from L2
        __builtin_nontemporal_store(s * (1.0f / 7.0f),
                                    out + (size_t)(r0 + r) * V_OUT + v);
    }
}

extern "C" void kernel_launch(void* const* d_in, const int* in_sizes, int n_in,
                              void* d_out, int out_size, void* d_ws, size_t ws_size,
                              hipStream_t stream) {
    const float* x    = (const float*)d_in[0];
    const int*   nidx = (const int*)d_in[1];
    float*       out  = (float*)d_out;

    icopool_gather<<<dim3(BLOCKS), dim3(TPB), 0, stream>>>(x, nidx, out);
}